// Round 2
// baseline (722.444 us; speedup 1.0000x reference)
//
#include <hip/hip_runtime.h>

#define SEQ   2048
#define BATCH 4096
#define HD    32

// ---------------- fast device math ----------------
__device__ __forceinline__ float exp2_fast(float a) {
#if __has_builtin(__builtin_amdgcn_exp2f)
    return __builtin_amdgcn_exp2f(a);
#else
    return exp2f(a);
#endif
}

__device__ __forceinline__ float rcp_fast(float a) {
#if __has_builtin(__builtin_amdgcn_rcpf)
    return __builtin_amdgcn_rcpf(a);
#else
    return 1.0f / a;
#endif
}

// tanh(x) = sign(x) * (1 - e^{-2|x|}) / (1 + e^{-2|x|})
__device__ __forceinline__ float fast_tanh(float v) {
    float ax = fabsf(v);
    float e  = exp2_fast(ax * -2.8853900817779268f);
    float r  = (1.0f - e) * rcp_fast(1.0f + e);
    return copysignf(r, v);
}

// DPP helpers. Established semantics (from working row_shr reduction):
//   row_shr:N -> dst[i] = src[i-N]        (0 shifted in w/ old=0)
//   row_ror:N -> dst[i] = src[(i-N)&15]   (full rotation, no invalid lanes)
template <int CTRL>
__device__ __forceinline__ float dpp_mov0(float v) {
    return __int_as_float(
        __builtin_amdgcn_update_dpp(0, __float_as_int(v), CTRL, 0xF, 0xF, false));
}

// ---------------- kernel ----------------
// 16 lanes per batch element; lane s owns h rows 2s, 2s+1.
// h-state exchange is pure in-register: iteration i uses row_ror:i of the own
// h-pair; W_hh rows are PRE-ROTATED per lane (wr[i] = W[r][2*((s-i)&15)..+1])
// so the register-array index is lane-uniform and static. No LDS, no barriers.
__global__ __launch_bounds__(256, 1) void rnn_elman_kernel(
    const float* __restrict__ x, const float* __restrict__ hidden,
    const float* __restrict__ W_ih, const float* __restrict__ b_ih,
    const float* __restrict__ W_hh, const float* __restrict__ b_hh,
    const float* __restrict__ W_fc, const float* __restrict__ b_fc,
    float* __restrict__ out)
{
    const int tid = threadIdx.x;
    const int s   = tid & 15;               // lane within element group (DPP-row aligned)
    const int eb  = tid >> 4;               // element within block
    const int e   = blockIdx.x * 16 + eb;   // global batch element
    const int r0  = 2 * s;
    const int r1  = 2 * s + 1;

    // ---- pre-rotated W_hh rows into registers ----
    // wr0[i] = (W[r0][2u], W[r0][2u+1]) with u = (s - i) & 15  (matches row_ror:i)
    float2 wr0[16], wr1[16];
    #pragma unroll
    for (int i = 0; i < 16; ++i) {
        const int u = (s - i) & 15;
        wr0[i] = *reinterpret_cast<const float2*>(W_hh + r0 * HD + 2 * u);
        wr1[i] = *reinterpret_cast<const float2*>(W_hh + r1 * HD + 2 * u);
    }
    const float wih0  = W_ih[r0], wih1 = W_ih[r1];
    const float bias0 = b_ih[r0] + b_hh[r0];
    const float bias1 = b_ih[r1] + b_hh[r1];
    const float wfc0  = W_fc[r0], wfc1 = W_fc[r1];
    const float bfc   = b_fc[0];

    // ---- own hidden state in registers ----
    float h0 = hidden[e * HD + r0];
    float h1 = hidden[e * HD + r1];

    // ---- x prefetch pipe (distance 4) ----
    float xq0 = x[0 * BATCH + e];
    float xq1 = x[1 * BATCH + e];
    float xq2 = x[2 * BATCH + e];
    float xq3 = x[3 * BATCH + e];

    #pragma unroll 4
    for (int t = 0; t < SEQ; ++t) {
        const float xv = xq0;
        xq0 = xq1; xq1 = xq2; xq2 = xq3;
        {
            int tt = t + 4; tt = tt < SEQ - 1 ? tt : SEQ - 1;
            xq3 = x[tt * BATCH + e];
        }

        // ---- matvec: rotate own h-pair across the 16 lanes, 4 FMAs per rotation ----
        float a0a = fmaf(xv, wih0, bias0);
        float a1a = fmaf(xv, wih1, bias1);
        float a0b = 0.f, a0c = 0.f, a0d = 0.f;
        float a1b = 0.f, a1c = 0.f, a1d = 0.f;

        // i = 0: own pair, no DPP
        a0a = fmaf(wr0[0].x, h0, a0a);
        a0b = fmaf(wr0[0].y, h1, a0b);
        a1a = fmaf(wr1[0].x, h0, a1a);
        a1b = fmaf(wr1[0].y, h1, a1b);

        #define MV_STEP(i)                                                    \
        {                                                                     \
            const float hx = dpp_mov0<0x120 + (i)>(h0);                       \
            const float hy = dpp_mov0<0x120 + (i)>(h1);                       \
            if ((i) & 1) {                                                    \
                a0c = fmaf(wr0[i].x, hx, a0c);                                \
                a0d = fmaf(wr0[i].y, hy, a0d);                                \
                a1c = fmaf(wr1[i].x, hx, a1c);                                \
                a1d = fmaf(wr1[i].y, hy, a1d);                                \
            } else {                                                          \
                a0a = fmaf(wr0[i].x, hx, a0a);                                \
                a0b = fmaf(wr0[i].y, hy, a0b);                                \
                a1a = fmaf(wr1[i].x, hx, a1a);                                \
                a1b = fmaf(wr1[i].y, hy, a1b);                                \
            }                                                                 \
        }
        MV_STEP(1)  MV_STEP(2)  MV_STEP(3)  MV_STEP(4)  MV_STEP(5)
        MV_STEP(6)  MV_STEP(7)  MV_STEP(8)  MV_STEP(9)  MV_STEP(10)
        MV_STEP(11) MV_STEP(12) MV_STEP(13) MV_STEP(14) MV_STEP(15)
        #undef MV_STEP

        const float z0 = (a0a + a0b) + (a0c + a0d);
        const float z1 = (a1a + a1b) + (a1c + a1d);

        h0 = fast_tanh(z0);
        h1 = fast_tanh(z1);

        // ---- output projection: reduce over the 16-lane row via DPP row_shr ----
        float p = fmaf(h0, wfc0, h1 * wfc1);
        p += dpp_mov0<0x111>(p);   // row_shr:1
        p += dpp_mov0<0x112>(p);   // row_shr:2
        p += dpp_mov0<0x114>(p);   // row_shr:4
        p += dpp_mov0<0x118>(p);   // row_shr:8  -> lane 15 holds the full sum
        if (s == 15) out[t * BATCH + e] = p + bfc;
    }
}

// ---------------- launch ----------------
extern "C" void kernel_launch(void* const* d_in, const int* in_sizes, int n_in,
                              void* d_out, int out_size, void* d_ws, size_t ws_size,
                              hipStream_t stream) {
    const float* x    = (const float*)d_in[0];
    const float* hid  = (const float*)d_in[1];
    const float* W_ih = (const float*)d_in[2];
    const float* b_ih = (const float*)d_in[3];
    const float* W_hh = (const float*)d_in[4];
    const float* b_hh = (const float*)d_in[5];
    const float* W_fc = (const float*)d_in[6];
    const float* b_fc = (const float*)d_in[7];
    float* out = (float*)d_out;

    dim3 grid(BATCH / 16);   // 256 blocks -> 1 block/CU
    dim3 block(256);         // 4 waves/block, 1 wave/SIMD
    rnn_elman_kernel<<<grid, block, 0, stream>>>(x, hid, W_ih, b_ih, W_hh, b_hh,
                                                 W_fc, b_fc, out);
}

// Round 4
// 628.330 us; speedup vs baseline: 1.1498x; 1.1498x over previous
//
#include <hip/hip_runtime.h>

#define SEQ   2048
#define BATCH 4096
#define HD    32

// ---------------- fast device math ----------------
__device__ __forceinline__ float exp2_fast(float a) {
#if __has_builtin(__builtin_amdgcn_exp2f)
    return __builtin_amdgcn_exp2f(a);
#else
    return exp2f(a);
#endif
}

__device__ __forceinline__ float rcp_fast(float a) {
#if __has_builtin(__builtin_amdgcn_rcpf)
    return __builtin_amdgcn_rcpf(a);
#else
    return 1.0f / a;
#endif
}

// tanh(x) = sign(x) * (1 - e^{-2|x|}) / (1 + e^{-2|x|})
__device__ __forceinline__ float fast_tanh(float v) {
    float ax = fabsf(v);
    float e  = exp2_fast(ax * -2.8853900817779268f);
    float r  = (1.0f - e) * rcp_fast(1.0f + e);
    return copysignf(r, v);
}

// Single-instruction DPP mov (ctrl must be a compile-time constant -> template).
// bound_ctrl=true: invalid lanes read 0 (correct for row_shr reduction;
// irrelevant for row_ror which has no invalid lanes).
template <int CTRL>
__device__ __forceinline__ float dpp_movf(float v) {
#if __has_builtin(__builtin_amdgcn_mov_dpp)
    return __int_as_float(
        __builtin_amdgcn_mov_dpp(__float_as_int(v), CTRL, 0xF, 0xF, true));
#else
    return __int_as_float(
        __builtin_amdgcn_update_dpp(0, __float_as_int(v), CTRL, 0xF, 0xF, false));
#endif
}
#define DPPF(v, c) dpp_movf<(c)>(v)

// ---------------- kernel ----------------
// 16 lanes per batch element; lane s owns h rows 2s, 2s+1 (one "pair").
// Broadcast of the 16 h-pairs per step is SPLIT across pipes:
//   pairs u=(s-i)&15, i=0..11  -> in-register via DPP row_ror:i (VALU pipe)
//   pairs u=(s+j)&15, j=1..4   -> via LDS ds_read_b64 (issued at TOP of step,
//                                 data written at end of previous step, so
//                                 ~120cyc LDS latency hides under DPP/FMA work)
// Weights are pre-rotated per lane so all register indices are static.
__global__ __launch_bounds__(256, 1) void rnn_elman_kernel(
    const float* __restrict__ x, const float* __restrict__ hidden,
    const float* __restrict__ W_ih, const float* __restrict__ b_ih,
    const float* __restrict__ W_hh, const float* __restrict__ b_hh,
    const float* __restrict__ W_fc, const float* __restrict__ b_fc,
    float* __restrict__ out)
{
    // 16 elements/block, slot stride 34 floats (136 B): 8B-aligned for b64,
    // rotates banks by 2 per element group -> conflict-free.
    __shared__ float sh[16 * 34];

    const int tid = threadIdx.x;
    const int s   = tid & 15;               // lane within element group
    const int eb  = tid >> 4;               // element within block
    const int e   = blockIdx.x * 16 + eb;   // global batch element
    const int r0  = 2 * s;
    const int r1  = 2 * s + 1;

    // ---- pre-rotated W_hh rows into registers ----
    // DPP part: wr[i] matches row_ror:i  (u = (s-i)&15), i = 0..11
    float2 wr0[12], wr1[12];
    #pragma unroll
    for (int i = 0; i < 12; ++i) {
        const int u = (s - i) & 15;
        wr0[i] = *reinterpret_cast<const float2*>(W_hh + r0 * HD + 2 * u);
        wr1[i] = *reinterpret_cast<const float2*>(W_hh + r1 * HD + 2 * u);
    }
    // LDS part: wl[j] matches pair u = (s+1+j)&15, j = 0..3
    float2 wl0[4], wl1[4];
    #pragma unroll
    for (int j = 0; j < 4; ++j) {
        const int u = (s + 1 + j) & 15;
        wl0[j] = *reinterpret_cast<const float2*>(W_hh + r0 * HD + 2 * u);
        wl1[j] = *reinterpret_cast<const float2*>(W_hh + r1 * HD + 2 * u);
    }
    const float wih0  = W_ih[r0], wih1 = W_ih[r1];
    const float bias0 = b_ih[r0] + b_hh[r0];
    const float bias1 = b_ih[r1] + b_hh[r1];
    const float wfc0  = W_fc[r0], wfc1 = W_fc[r1];
    const float bfc   = b_fc[0];

    // ---- loop-invariant LDS pointers ----
    float* slot = sh + eb * 34;
    float2* wp = reinterpret_cast<float2*>(slot + 2 * s);           // own pair
    const float2* rp0 = reinterpret_cast<const float2*>(slot + 2 * ((s + 1) & 15));
    const float2* rp1 = reinterpret_cast<const float2*>(slot + 2 * ((s + 2) & 15));
    const float2* rp2 = reinterpret_cast<const float2*>(slot + 2 * ((s + 3) & 15));
    const float2* rp3 = reinterpret_cast<const float2*>(slot + 2 * ((s + 4) & 15));

    // ---- own hidden state ----
    float h0 = hidden[e * HD + r0];
    float h1 = hidden[e * HD + r1];
    *wp = make_float2(h0, h1);
    __builtin_amdgcn_wave_barrier();

    // ---- x prefetch pipe (distance 4) ----
    float xq0 = x[0 * BATCH + e];
    float xq1 = x[1 * BATCH + e];
    float xq2 = x[2 * BATCH + e];
    float xq3 = x[3 * BATCH + e];

    #pragma unroll 4
    for (int t = 0; t < SEQ; ++t) {
        // ---- issue LDS reads of pairs (s+1..s+4) FIRST (data from prev step) ----
        const float2 hp0 = *rp0;
        const float2 hp1 = *rp1;
        const float2 hp2 = *rp2;
        const float2 hp3 = *rp3;

        const float xv = xq0;
        xq0 = xq1; xq1 = xq2; xq2 = xq3;
        {
            int tt = t + 4; tt = tt < SEQ - 1 ? tt : SEQ - 1;
            xq3 = x[tt * BATCH + e];
        }

        // ---- matvec: 8 independent FMA chains ----
        float a0a = fmaf(xv, wih0, bias0);
        float a1a = fmaf(xv, wih1, bias1);
        float a0b = 0.f, a0c = 0.f, a0d = 0.f;
        float a1b = 0.f, a1c = 0.f, a1d = 0.f;

        // i = 0: own pair (no DPP)
        a0a = fmaf(wr0[0].x, h0, a0a);
        a0b = fmaf(wr0[0].y, h1, a0b);
        a1a = fmaf(wr1[0].x, h0, a1a);
        a1b = fmaf(wr1[0].y, h1, a1b);

        // i = 1..11: DPP row_ror
        #define MV_STEP(i)                                                    \
        {                                                                     \
            const float hx = DPPF(h0, 0x120 + (i));                           \
            const float hy = DPPF(h1, 0x120 + (i));                           \
            if ((i) & 1) {                                                    \
                a0c = fmaf(wr0[i].x, hx, a0c);                                \
                a0d = fmaf(wr0[i].y, hy, a0d);                                \
                a1c = fmaf(wr1[i].x, hx, a1c);                                \
                a1d = fmaf(wr1[i].y, hy, a1d);                                \
            } else {                                                          \
                a0a = fmaf(wr0[i].x, hx, a0a);                                \
                a0b = fmaf(wr0[i].y, hy, a0b);                                \
                a1a = fmaf(wr1[i].x, hx, a1a);                                \
                a1b = fmaf(wr1[i].y, hy, a1b);                                \
            }                                                                 \
        }
        MV_STEP(1)  MV_STEP(2)  MV_STEP(3)  MV_STEP(4)  MV_STEP(5)
        MV_STEP(6)  MV_STEP(7)  MV_STEP(8)  MV_STEP(9)  MV_STEP(10)
        MV_STEP(11)
        #undef MV_STEP

        // pairs from LDS (u = s+1..s+4)
        a0a = fmaf(wl0[0].x, hp0.x, a0a);
        a0b = fmaf(wl0[0].y, hp0.y, a0b);
        a1a = fmaf(wl1[0].x, hp0.x, a1a);
        a1b = fmaf(wl1[0].y, hp0.y, a1b);
        a0c = fmaf(wl0[1].x, hp1.x, a0c);
        a0d = fmaf(wl0[1].y, hp1.y, a0d);
        a1c = fmaf(wl1[1].x, hp1.x, a1c);
        a1d = fmaf(wl1[1].y, hp1.y, a1d);
        a0a = fmaf(wl0[2].x, hp2.x, a0a);
        a0b = fmaf(wl0[2].y, hp2.y, a0b);
        a1a = fmaf(wl1[2].x, hp2.x, a1a);
        a1b = fmaf(wl1[2].y, hp2.y, a1b);
        a0c = fmaf(wl0[3].x, hp3.x, a0c);
        a0d = fmaf(wl0[3].y, hp3.y, a0d);
        a1c = fmaf(wl1[3].x, hp3.x, a1c);
        a1d = fmaf(wl1[3].y, hp3.y, a1d);

        const float z0 = (a0a + a0b) + (a0c + a0d);
        const float z1 = (a1a + a1b) + (a1c + a1d);

        h0 = fast_tanh(z0);
        h1 = fast_tanh(z1);

        // ---- publish own pair for next step ----
        *wp = make_float2(h0, h1);

        // ---- output projection (overlaps write->next-read distance) ----
        float p = fmaf(h0, wfc0, h1 * wfc1);
        p += DPPF(p, 0x111);   // row_shr:1
        p += DPPF(p, 0x112);   // row_shr:2
        p += DPPF(p, 0x114);   // row_shr:4
        p += DPPF(p, 0x118);   // row_shr:8 -> lane 15 holds the sum
        if (s == 15) out[t * BATCH + e] = p + bfc;

        __builtin_amdgcn_wave_barrier();
    }
}

// ---------------- launch ----------------
extern "C" void kernel_launch(void* const* d_in, const int* in_sizes, int n_in,
                              void* d_out, int out_size, void* d_ws, size_t ws_size,
                              hipStream_t stream) {
    const float* x    = (const float*)d_in[0];
    const float* hid  = (const float*)d_in[1];
    const float* W_ih = (const float*)d_in[2];
    const float* b_ih = (const float*)d_in[3];
    const float* W_hh = (const float*)d_in[4];
    const float* b_hh = (const float*)d_in[5];
    const float* W_fc = (const float*)d_in[6];
    const float* b_fc = (const float*)d_in[7];
    float* out = (float*)d_out;

    dim3 grid(BATCH / 16);   // 256 blocks -> 1 block/CU
    dim3 block(256);         // 4 waves/block, 1 wave/SIMD
    rnn_elman_kernel<<<grid, block, 0, stream>>>(x, hid, W_ih, b_ih, W_hh, b_hh,
                                                 W_fc, b_fc, out);
}